// Round 5
// baseline (147.682 us; speedup 1.0000x reference)
//
#include <hip/hip_runtime.h>
#include <hip/hip_bf16.h>
#include <cstddef>

// out[b,d,p] = sum_{t=0..62} filt[t] * act[b, (d+31-t) & 511, p]
// Banded circulant via mfma_f32_32x32x16_bf16 (6 K-blocks per 32-row d-tile).
// Persistent blocks (grid = 1024 = 4 blocks/CU resident), single 32 KB LDS
// buffer, register-held prefetch of the next tile issued before compute.

#define NC    512
#define HW    3136          // 56*56
#define NT    32            // hw positions per tile
#define NTILE 98            // tiles per batch
#define NB    32
#define TPB   256
#define GRID  1024          // 4 blocks/CU x 256 CU
#define TOTT  (NB * NTILE)  // 3136 tiles

typedef __attribute__((ext_vector_type(8)))  short bf16x8;
typedef __attribute__((ext_vector_type(4)))  float f32x4;
typedef __attribute__((ext_vector_type(16))) float f32x16;

__device__ __forceinline__ short f2bf(float f) {
    union { __hip_bfloat16 h; short s; } u;
    u.h = __float2bfloat16(f);
    return u.s;
}

__device__ __forceinline__ int swzf(int hw) {
    return (((hw & 7) ^ (hw >> 3)) << 4);
}

__device__ __forceinline__ void load_tile(const float* __restrict__ gb,
                                          int wv, int g, int q, f32x4 (&r)[16]) {
    #pragma unroll
    for (int j = 0; j < 8; ++j) {
        const int r0 = wv * 128 + j * 16 + 2 * g;
        r[2 * j]     = *reinterpret_cast<const f32x4*>(gb + (size_t)r0 * HW + 4 * q);
        r[2 * j + 1] = *reinterpret_cast<const f32x4*>(gb + (size_t)(r0 + 1) * HW + 4 * q);
    }
}

__device__ __forceinline__ void store_tile(unsigned short* __restrict__ dst,
                                           int wv, int g, int q, const f32x4 (&r)[16]) {
    #pragma unroll
    for (int j = 0; j < 8; ++j) {
        const int r0 = wv * 128 + j * 16 + 2 * g;
        #pragma unroll
        for (int t4 = 0; t4 < 4; ++t4) {
            const int hw = 4 * q + t4;
            const unsigned int pk = (unsigned int)(unsigned short)f2bf(r[2 * j][t4])
                                  | ((unsigned int)(unsigned short)f2bf(r[2 * j + 1][t4]) << 16);
            const int byte = hw * (NC * 2) + ((r0 * 2) ^ swzf(hw));
            *reinterpret_cast<unsigned int*>(reinterpret_cast<char*>(dst) + byte) = pk;
        }
    }
}

__global__ __launch_bounds__(TPB, 4)
void toeplitz_persist_kernel(const float* __restrict__ act,
                             const float* __restrict__ filt,
                             float* __restrict__ out) {
    // bf16 x-tile [hw][c]: byte = hw*1024 + ((c*2) ^ swzf(hw)).  32 KB.
    __shared__ __align__(16) unsigned short xs[NT * NC];

    const int tid = threadIdx.x;
    const int wv  = tid >> 6;
    const int ln  = tid & 63;
    const int bx  = blockIdx.x;

    // ---- A fragments: A_delta[r,k] = filt[delta + 31 + r - k] (0 outside)
    // lane: r = ln&31, k = (ln>>5)*8 + i.  delta(m) = 32 - 16*m, m=0..5
    const int r_a = ln & 31;
    const int k0  = (ln >> 5) * 8;
    bf16x8 af[6];
    #pragma unroll
    for (int m = 0; m < 6; ++m) {
        const int delta = 32 - 16 * m;
        #pragma unroll
        for (int i = 0; i < 8; ++i) {
            const int t = delta + 31 + r_a - (k0 + i);
            af[m][i] = (t >= 0 && t < 63) ? f2bf(filt[t]) : (short)0;
        }
    }

    const int g = ln >> 3;      // 0..7 row-pair group
    const int q = ln & 7;       // hw quad

    const int hwl     = ln & 31;
    const int rowbyte = hwl * (NC * 2);
    const int swzv    = swzf(hwl);
    const int kbv     = (ln >> 5) * 16;
    const int rhalf   = (ln >> 5) * 4;
    const int cbase   = wv * 128 - 32;

    // ---- prologue: stage first tile
    f32x4 R[16];
    {
        const int b  = bx / NTILE;
        const int pr = bx - b * NTILE;
        load_tile(act + (size_t)b * NC * HW + (size_t)pr * NT, wv, g, q, R);
        store_tile(xs, wv, g, q, R);
    }
    __syncthreads();

    for (int t = bx; t < TOTT; t += GRID) {
        const int tn = t + GRID;
        const bool has_next = tn < TOTT;

        // issue next tile's loads before compute (latency hides under MFMA/stores)
        if (has_next) {
            const int bn  = tn / NTILE;
            const int prn = tn - bn * NTILE;
            load_tile(act + (size_t)bn * NC * HW + (size_t)prn * NT, wv, g, q, R);
        }

        // compute current tile from xs
        const int b  = t / NTILE;
        const int pr = t - b * NTILE;
        bf16x8 w[12];
        #pragma unroll
        for (int u = 0; u < 12; ++u) {
            const int c0 = (cbase + 16 * u) & (NC - 1);
            w[u] = *reinterpret_cast<const bf16x8*>(
                reinterpret_cast<const char*>(xs) + rowbyte + (((c0 * 2) + kbv) ^ swzv));
        }
        float* ob = out + (size_t)b * NC * HW + (size_t)pr * NT + hwl;
        #pragma unroll
        for (int j = 0; j < 4; ++j) {
            const int d0 = wv * 128 + j * 32;
            f32x16 acc;
            #pragma unroll
            for (int r = 0; r < 16; ++r) acc[r] = 0.0f;
            #pragma unroll
            for (int m = 0; m < 6; ++m)     // c0 = d0-32+16m, delta = 32-16m
                acc = __builtin_amdgcn_mfma_f32_32x32x16_bf16(af[m], w[2 * j + m], acc, 0, 0, 0);
            #pragma unroll
            for (int r = 0; r < 16; ++r) {
                const int row = d0 + (r & 3) + 8 * (r >> 2) + rhalf;
                __builtin_nontemporal_store(acc[r], ob + (size_t)row * HW);
            }
        }

        __syncthreads();            // all waves done reading xs
        if (has_next) {
            store_tile(xs, wv, g, q, R);   // waits on R's loads (long landed)
            __syncthreads();               // xs published for next iter
        }
    }
}

extern "C" void kernel_launch(void* const* d_in, const int* in_sizes, int n_in,
                              void* d_out, int out_size, void* d_ws, size_t ws_size,
                              hipStream_t stream) {
    const float* act  = (const float*)d_in[0];   // (32, 512, 56, 56) f32
    const float* filt = (const float*)d_in[1];   // (1, 1, 63) f32
    float* out = (float*)d_out;                  // (32, 512, 56, 56) f32
    dim3 grid(GRID);
    dim3 block(TPB);
    hipLaunchKernelGGL(toeplitz_persist_kernel, grid, block, 0, stream,
                       act, filt, out);
}

// Round 6
// 79.925 us; speedup vs baseline: 1.8478x; 1.8478x over previous
//
#include <hip/hip_runtime.h>
#include <hip/hip_bf16.h>
#include <cstddef>

// out[b,d,p] = sum_{t=0..62} filt[t] * act[b, (d+31-t) & 511, p]
// Banded circulant via mfma_f32_32x32x16_bf16, ZERO-LDS version:
// each wave loads its B-fragments straight from global (coalesced 128B rows)
// into registers, converts to bf16, MFMAs. No barriers, no staging.
// Fragment window w0..w11 slides across the 4 d-tiles (2 new per tile).

#define NC    512
#define HW    3136          // 56*56
#define NT    32            // hw positions per block
#define NTILE 98
#define NB    32
#define TPB   256

typedef __attribute__((ext_vector_type(8)))  short bf16x8;
typedef __attribute__((ext_vector_type(16))) float f32x16;

__device__ __forceinline__ short f2bf(float f) {
    union { __hip_bfloat16 h; short s; } u;
    u.h = __float2bfloat16(f);
    return u.s;
}

// B-fragment for 16-row c-block starting at (uniform) row0:
// lane (col=ln&31 -> hw, k=kh*8+i -> row row0+kh*8+i).  base already
// includes b, hw0, col and kh*8 row offset.
__device__ __forceinline__ bf16x8 load_frag(const float* __restrict__ base,
                                            int row0) {
    float f[8];
    #pragma unroll
    for (int i = 0; i < 8; ++i)
        f[i] = base[(size_t)(row0 + i) * HW];
    bf16x8 w;
    #pragma unroll
    for (int i = 0; i < 8; ++i)
        w[i] = f2bf(f[i]);
    return w;
}

__global__ __launch_bounds__(TPB, 4)
void toeplitz_direct_kernel(const float* __restrict__ act,
                            const float* __restrict__ filt,
                            float* __restrict__ out) {
    const int tid = threadIdx.x;
    const int wv  = tid >> 6;          // wave 0..3 -> d-range wv*128..+127
    const int ln  = tid & 63;
    const int bx  = blockIdx.x;
    const int b   = bx / NTILE;
    const int hw0 = (bx - b * NTILE) * NT;

    // ---- A fragments: A_delta[r,k] = filt[delta + 31 + r - k] (0 outside)
    // lane: r = ln&31, k = (ln>>5)*8 + i.  delta(m) = 32 - 16*m, m=0..5
    const int r_a = ln & 31;
    const int k0  = (ln >> 5) * 8;
    bf16x8 af[6];
    #pragma unroll
    for (int m = 0; m < 6; ++m) {
        const int delta = 32 - 16 * m;
        #pragma unroll
        for (int i = 0; i < 8; ++i) {
            const int t = delta + 31 + r_a - (k0 + i);
            af[m][i] = (t >= 0 && t < 63) ? f2bf(filt[t]) : (short)0;
        }
    }

    const int col = ln & 31;           // hw within tile
    const int kh  = ln >> 5;           // k-half
    const float* base = act + (size_t)b * NC * HW + hw0 + col
                            + (size_t)kh * 8 * HW;
    float* ob = out + (size_t)b * NC * HW + hw0 + col;
    const int rhalf = kh * 4;
    const int cb    = wv * 128 - 32;   // first c-block of this wave

    // row0 of c-block u (u=0..11); aligned 16-row blocks never straddle wrap
    #define ROW0(u) ((cb + 16 * (u) + NC) & (NC - 1))

    #define DO_TILE(j, wa, wb, wc, wd, we, wf)                                 \
    {                                                                          \
        const int d0 = wv * 128 + (j) * 32;                                    \
        f32x16 acc;                                                            \
        _Pragma("unroll") for (int r = 0; r < 16; ++r) acc[r] = 0.0f;          \
        acc = __builtin_amdgcn_mfma_f32_32x32x16_bf16(af[0], wa, acc, 0, 0, 0);\
        acc = __builtin_amdgcn_mfma_f32_32x32x16_bf16(af[1], wb, acc, 0, 0, 0);\
        acc = __builtin_amdgcn_mfma_f32_32x32x16_bf16(af[2], wc, acc, 0, 0, 0);\
        acc = __builtin_amdgcn_mfma_f32_32x32x16_bf16(af[3], wd, acc, 0, 0, 0);\
        acc = __builtin_amdgcn_mfma_f32_32x32x16_bf16(af[4], we, acc, 0, 0, 0);\
        acc = __builtin_amdgcn_mfma_f32_32x32x16_bf16(af[5], wf, acc, 0, 0, 0);\
        _Pragma("unroll") for (int r = 0; r < 16; ++r) {                       \
            const int row = d0 + (r & 3) + 8 * (r >> 2) + rhalf;               \
            __builtin_nontemporal_store(acc[r], ob + (size_t)row * HW);        \
        }                                                                      \
    }

    bf16x8 w0 = load_frag(base, ROW0(0));
    bf16x8 w1 = load_frag(base, ROW0(1));
    bf16x8 w2 = load_frag(base, ROW0(2));
    bf16x8 w3 = load_frag(base, ROW0(3));
    bf16x8 w4 = load_frag(base, ROW0(4));
    bf16x8 w5 = load_frag(base, ROW0(5));
    DO_TILE(0, w0, w1, w2, w3, w4, w5)

    bf16x8 w6 = load_frag(base, ROW0(6));
    bf16x8 w7 = load_frag(base, ROW0(7));
    DO_TILE(1, w2, w3, w4, w5, w6, w7)

    bf16x8 w8 = load_frag(base, ROW0(8));
    bf16x8 w9 = load_frag(base, ROW0(9));
    DO_TILE(2, w4, w5, w6, w7, w8, w9)

    bf16x8 wA = load_frag(base, ROW0(10));
    bf16x8 wB = load_frag(base, ROW0(11));
    DO_TILE(3, w6, w7, w8, w9, wA, wB)

    #undef DO_TILE
    #undef ROW0
}

extern "C" void kernel_launch(void* const* d_in, const int* in_sizes, int n_in,
                              void* d_out, int out_size, void* d_ws, size_t ws_size,
                              hipStream_t stream) {
    const float* act  = (const float*)d_in[0];   // (32, 512, 56, 56) f32
    const float* filt = (const float*)d_in[1];   // (1, 1, 63) f32
    float* out = (float*)d_out;                  // (32, 512, 56, 56) f32
    dim3 grid(NB * NTILE);    // 3136
    dim3 block(TPB);
    hipLaunchKernelGGL(toeplitz_direct_kernel, grid, block, 0, stream,
                       act, filt, out);
}

// Round 7
// 69.132 us; speedup vs baseline: 2.1362x; 1.1561x over previous
//
#include <hip/hip_runtime.h>
#include <hip/hip_bf16.h>
#include <cstddef>

// out[b,d,p] = sum_{t=0..62} filt[t] * act[b, (d+31-t) & 511, p]
// Banded circulant via mfma_f32_32x32x16_bf16: per 32-row d-tile, 6 aligned
// K=16 c-blocks cover the band. C/D layout col=lane&31 -> full 128B-line
// stores. x staged in LDS bf16 [hw][c], swz(hw)=(((hw&7)^(hw>>3))<<4).
// Round 7: identical to round 3 except __launch_bounds__(256,5) -> 5
// blocks/CU (5 x 32 KB = 160 KB LDS, the full pool) for +25% resident waves.

#define NC    512
#define HW    3136          // 56*56
#define NT    32            // hw positions per block
#define NTILE (HW / NT)     // 98
#define NB    32
#define TPB   256

typedef __attribute__((ext_vector_type(8)))  short bf16x8;
typedef __attribute__((ext_vector_type(4)))  float f32x4;
typedef __attribute__((ext_vector_type(16))) float f32x16;

__device__ __forceinline__ short f2bf(float f) {
    union { __hip_bfloat16 h; short s; } u;
    u.h = __float2bfloat16(f);
    return u.s;
}

__device__ __forceinline__ int swzf(int hw) {
    return (((hw & 7) ^ (hw >> 3)) << 4);
}

__global__ __launch_bounds__(TPB, 5)
void toeplitz_mfma32_kernel(const float* __restrict__ act,
                            const float* __restrict__ filt,
                            float* __restrict__ out) {
    // bf16 x-tile [hw][c]: byte = hw*1024 + ((c*2) ^ swzf(hw)).  32 KB.
    __shared__ __align__(16) unsigned short xs[NT * NC];

    const int tid  = threadIdx.x;
    const int wv   = tid >> 6;          // wave 0..3
    const int ln   = tid & 63;
    const int bx   = blockIdx.x;
    const int b    = bx / NTILE;
    const int tile = bx - b * NTILE;
    const int hw0  = tile * NT;

    // ---- A fragments: A_delta[r,k] = filt[delta + 31 + r - k] (0 outside)
    // lane: r = ln&31, k = (ln>>5)*8 + i.  delta(m) = 32 - 16*m, m=0..5
    const int r_a = ln & 31;
    const int k0  = (ln >> 5) * 8;
    bf16x8 af[6];
    #pragma unroll
    for (int m = 0; m < 6; ++m) {
        const int delta = 32 - 16 * m;
        #pragma unroll
        for (int i = 0; i < 8; ++i) {
            const int t = delta + 31 + r_a - (k0 + i);
            af[m][i] = (t >= 0 && t < 63) ? f2bf(filt[t]) : (short)0;
        }
    }

    // ---- stage x[b][:, hw0:hw0+32] -> LDS bf16 [hw][c] (transpose).
    // Per instr: 8 rows x 128 B contiguous global; paired rows -> b32 writes.
    {
        const float* gb = act + (size_t)b * NC * HW + hw0;
        const int g = ln >> 3;      // 0..7 row-pair group
        const int q = ln & 7;       // hw quad
        #pragma unroll
        for (int j = 0; j < 8; ++j) {
            const int r0 = wv * 128 + j * 16 + 2 * g;   // even row
            const f32x4 a0 = *reinterpret_cast<const f32x4*>(gb + (size_t)r0 * HW + 4 * q);
            const f32x4 a1 = *reinterpret_cast<const f32x4*>(gb + (size_t)(r0 + 1) * HW + 4 * q);
            #pragma unroll
            for (int t4 = 0; t4 < 4; ++t4) {
                const int hw = 4 * q + t4;
                const unsigned int pk = (unsigned int)(unsigned short)f2bf(a0[t4])
                                      | ((unsigned int)(unsigned short)f2bf(a1[t4]) << 16);
                const int byte = hw * (NC * 2) + ((r0 * 2) ^ swzf(hw));
                *reinterpret_cast<unsigned int*>(reinterpret_cast<char*>(xs) + byte) = pk;
            }
        }
    }
    __syncthreads();

    // ---- compute: wave wv owns d-tiles d0 = wv*128 + j*32, j=0..3.
    // B-frag for c-block c0: lane col = ln&31 (hw), k = (ln>>5)*8+i.
    const int hwl  = ln & 31;
    const int rowbyte = hwl * (NC * 2);
    const int swzv    = swzf(hwl);
    const int kb      = (ln >> 5) * 16;   // byte offset of k-half

    #define BFRAG(c0) (*reinterpret_cast<const bf16x8*>(                      \
        reinterpret_cast<const char*>(xs) +                                   \
        (rowbyte + (((((c0) & (NC - 1)) * 2) + kb) ^ swzv))))

    // 12 c-blocks per wave: c0 = wv*128 - 32 + 16*i, i=0..11 (each reused 3x)
    bf16x8 w[12];
    {
        const int cbase = wv * 128 - 32;
        #pragma unroll
        for (int i = 0; i < 12; ++i)
            w[i] = BFRAG(cbase + 16 * i);
    }

    float* ob = out + (size_t)b * NC * HW + hw0 + hwl;
    const int rhalf = (ln >> 5) * 4;

    #pragma unroll
    for (int j = 0; j < 4; ++j) {
        const int d0 = wv * 128 + j * 32;
        f32x16 acc;
        #pragma unroll
        for (int r = 0; r < 16; ++r) acc[r] = 0.0f;
        #pragma unroll
        for (int m = 0; m < 6; ++m)     // c0 = d0-32+16m, delta = 32-16m
            acc = __builtin_amdgcn_mfma_f32_32x32x16_bf16(af[m], w[2 * j + m], acc, 0, 0, 0);
        #pragma unroll
        for (int r = 0; r < 16; ++r) {
            const int row = d0 + (r & 3) + 8 * (r >> 2) + rhalf;
            __builtin_nontemporal_store(acc[r], ob + (size_t)row * HW);
        }
    }
    #undef BFRAG
}

extern "C" void kernel_launch(void* const* d_in, const int* in_sizes, int n_in,
                              void* d_out, int out_size, void* d_ws, size_t ws_size,
                              hipStream_t stream) {
    const float* act  = (const float*)d_in[0];   // (32, 512, 56, 56) f32
    const float* filt = (const float*)d_in[1];   // (1, 1, 63) f32
    float* out = (float*)d_out;                  // (32, 512, 56, 56) f32
    dim3 grid(NB * NTILE);    // 3136
    dim3 block(TPB);
    hipLaunchKernelGGL(toeplitz_mfma32_kernel, grid, block, 0, stream,
                       act, filt, out);
}